// Round 12
// baseline (3331.743 us; speedup 1.0000x reference)
//
#include <hip/hip_runtime.h>
#include <math.h>
#include <stdint.h>

#define CC 512
#define NN 4096
#define BB 4

typedef _Float16 f16;
typedef _Float16 f16x8 __attribute__((ext_vector_type(8)));
typedef _Float16 f16x4 __attribute__((ext_vector_type(4)));
typedef float f32x4 __attribute__((ext_vector_type(4)));

// ---------- async global->LDS 16B ----------
__device__ __forceinline__ void gload_lds16(const void* g, void* l) {
    __builtin_amdgcn_global_load_lds(
        (const __attribute__((address_space(1))) void*)g,
        (__attribute__((address_space(3))) void*)l, 16, 0, 0);
}

// Stage ROWS rows x 64 f16 from K-major global into linear LDS; source pre-swizzled.
template<int ROWS>
__device__ __forceinline__ void stage_tile(const f16* __restrict__ g, int stride_e,
                                           f16* lds, int wid, int lane) {
    constexpr int ITERS = ROWS * 8 / 64 / 4;   // 4 waves
    #pragma unroll
    for (int it = 0; it < ITERS; ++it) {
        int flatbase = (wid * ITERS + it) * 64;
        f16* dst = lds + flatbase * 8;
        int flat = flatbase + lane;
        int r = flat >> 3, c = flat & 7;
        const f16* src = g + (size_t)r * stride_e + ((c ^ (r & 7)) << 3);
        gload_lds16(src, dst);
    }
}

__device__ __forceinline__ f16x8 frag_ld(const f16* lds, int r, int ch) {
    return *(const f16x8*)(lds + r * 64 + ((ch ^ (r & 7)) << 3));
}

#define MFMA16(a, b, c) __builtin_amdgcn_mfma_f32_16x16x32_f16((a), (b), (c), 0, 0, 0)

// ---------- DPP row_ror reductions over 16-lane rows (VALU only) ----------
template<int N>
__device__ __forceinline__ float ror16(float x) {
    return __int_as_float(__builtin_amdgcn_update_dpp(
        0, __float_as_int(x), 0x120 + N, 0xF, 0xF, true));
}
__device__ __forceinline__ f32x4 rmax16(f32x4 v) {
    #pragma unroll
    for (int q = 0; q < 4; ++q) {
        float x = v[q];
        x = fmaxf(x, ror16<1>(x));
        x = fmaxf(x, ror16<2>(x));
        x = fmaxf(x, ror16<4>(x));
        x = fmaxf(x, ror16<8>(x));
        v[q] = x;
    }
    return v;
}
__device__ __forceinline__ f32x4 rsum16(f32x4 v) {
    #pragma unroll
    for (int q = 0; q < 4; ++q) {
        float x = v[q];
        x += ror16<1>(x);
        x += ror16<2>(x);
        x += ror16<4>(x);
        x += ror16<8>(x);
        v[q] = x;
    }
    return v;
}

// ---------------- W conversion ----------------
__global__ __launch_bounds__(256) void wcvt_k(const float* __restrict__ Wb,
                                              const float* __restrict__ Wc,
                                              const float* __restrict__ Wd,
                                              f16* __restrict__ W16) {
    int i = blockIdx.x * 256 + threadIdx.x;
    int idx = i * 4;
    int m = idx >> 18;
    int off = idx & 262143;
    const float* src = (m == 0) ? Wb : (m == 1) ? Wc : Wd;
    f32x4 v = *(const f32x4*)(src + off);
    f16x4 h = { (f16)v[0], (f16)v[1], (f16)v[2], (f16)v[3] };
    *(f16x4*)(W16 + idx) = h;
}

// ---------------- proj (all batches): O = W @ x ----------------
__global__ __launch_bounds__(256) void proj_k(const float* __restrict__ x,
                                              const f16* __restrict__ W16,
                                              f16* __restrict__ Bt, f16* __restrict__ Ct,
                                              f16* __restrict__ Dm) {
    const int wsel = blockIdx.z % 3;
    const int b = blockIdx.z / 3;
    const f16* __restrict__ W = W16 + (size_t)wsel * CC * CC;
    const float* __restrict__ X = x + (size_t)b * CC * NN;
    const size_t p16 = (size_t)CC * NN;
    const int o0 = blockIdx.y * 128, n0 = blockIdx.x * 128;

    __shared__ __align__(16) char smraw[34816];
    f16* As = (f16*)smraw;
    f16* Bs = As + 128 * 64;
    f16* T  = (f16*)smraw;

    const int t = threadIdx.x;
    const int wid = t >> 6, lane = t & 63;
    const int wr = wid >> 1, wc = wid & 1;

    f32x4 acc[4][4] = {};
    const int cg = t & 7;
    const int n4 = ((t >> 3) & 31) * 4;

    for (int kc = 0; kc < CC; kc += 64) {
        __syncthreads();
        stage_tile<128>(W + (size_t)o0 * CC + kc, CC, As, wid, lane);
        f32x4 v[8];
        #pragma unroll
        for (int i = 0; i < 8; ++i)
            v[i] = *(const f32x4*)(X + (size_t)(kc + cg * 8 + i) * NN + n0 + n4);
        #pragma unroll
        for (int j = 0; j < 4; ++j) {
            f16x8 h = { (f16)v[0][j], (f16)v[1][j], (f16)v[2][j], (f16)v[3][j],
                        (f16)v[4][j], (f16)v[5][j], (f16)v[6][j], (f16)v[7][j] };
            int r = n4 + j;
            *(f16x8*)(Bs + r * 64 + ((cg ^ (r & 7)) << 3)) = h;
        }
        __syncthreads();
        #pragma unroll
        for (int ks = 0; ks < 2; ++ks) {
            int ch = ks * 4 + (lane >> 4);
            f16x8 a[4], bb[4];
            #pragma unroll
            for (int i = 0; i < 4; ++i) a[i]  = frag_ld(As, wr * 64 + i * 16 + (lane & 15), ch);
            #pragma unroll
            for (int j = 0; j < 4; ++j) bb[j] = frag_ld(Bs, wc * 64 + j * 16 + (lane & 15), ch);
            #pragma unroll
            for (int i = 0; i < 4; ++i)
                #pragma unroll
                for (int j = 0; j < 4; ++j)
                    acc[i][j] = MFMA16(a[i], bb[j], acc[i][j]);
        }
    }

    __syncthreads();
    if (wsel < 2) {
        #pragma unroll
        for (int i = 0; i < 4; ++i)
            #pragma unroll
            for (int j = 0; j < 4; ++j) {
                int n_l = wc * 64 + j * 16 + (lane & 15);
                int o_l = wr * 64 + i * 16 + (lane >> 4) * 4;
                f16x4 h = { (f16)acc[i][j][0], (f16)acc[i][j][1], (f16)acc[i][j][2], (f16)acc[i][j][3] };
                *(f16x4*)(T + n_l * 136 + o_l) = h;
            }
        __syncthreads();
        f16* __restrict__ dst = ((wsel == 0) ? Bt : Ct) + (size_t)b * p16;
        int n = t & 127;
        #pragma unroll
        for (int it = 0; it < 8; ++it) {
            int ch8 = (t >> 7) * 8 + it;
            f16x8 h = *(f16x8*)(T + n * 136 + ch8 * 8);
            *(f16x8*)(dst + (size_t)(n0 + n) * CC + o0 + ch8 * 8) = h;
        }
    } else {
        #pragma unroll
        for (int i = 0; i < 4; ++i)
            #pragma unroll
            for (int j = 0; j < 4; ++j) {
                int n_l = wc * 64 + j * 16 + (lane & 15);
                #pragma unroll
                for (int q = 0; q < 4; ++q) {
                    int o_l = wr * 64 + i * 16 + (lane >> 4) * 4 + q;
                    T[o_l * 136 + n_l] = (f16)acc[i][j][q];
                }
            }
        __syncthreads();
        f16* __restrict__ dst = Dm + (size_t)b * p16;
        int o = t & 127;
        #pragma unroll
        for (int it = 0; it < 8; ++it) {
            int ch8 = (t >> 7) * 8 + it;
            f16x8 h = *(f16x8*)(T + o * 136 + ch8 * 8);
            *(f16x8*)(dst + (size_t)(o0 + o) * NN + n0 + ch8 * 8) = h;
        }
    }
}

// ---------------- fused flash attention: balanced 2P/4C/2S ----------------
// Role placement balanced under BOTH candidate wave->SIMD mappings (wid%4, wid>>1):
//   producers {0,5}, stagers {1,4}, consumers {2,3,6,7}
//   wid%4 pairs: (0,4)=P+S (1,5)=S+P (2,6)=C+C (3,7)=C+C -> 64 MFMA each
//   wid>>1 pairs: (0,1)=P+S (4,5)=S+P (2,3)=C+C (6,7)=C+C -> 64 MFMA each
// Producers: QK^T reuse-2 (32 n-rows each, Q[2][16] in R-file), wave-local softmax,
//   T13 defer-rescale flag. Consumers: PV(i-1), O = 64n x 128c. Stagers: all staging,
//   Ct dbuf + Dt dbuf. ONE barrier/iter. (r11 regression = unbalanced placement.)
__global__ __launch_bounds__(512) void flash_k(
    const float* __restrict__ x, const float* __restrict__ gamma_p,
    const f16* __restrict__ Bt, const f16* __restrict__ Ct,
    const f16* __restrict__ Dm, float* __restrict__ out)
{
    __shared__ __align__(16) char sm[140064];
    f16*   CtB  = (f16*)sm;                    // [2][32][512]  65536 B
    f16*   DtB  = (f16*)(sm + 65536);          // [2][512][32]  65536 B
    f16*   PSB  = (f16*)(sm + 131072);         // [2][64][32]    8192 B
    float* SCL  = (float*)(sm + 139264);       // [2][64]         512 B
    int*   FLG  = (int*)(sm + 139776);         // [2][2]           16 B
    float* LROW = (float*)(sm + 139792);       // [64]            256 B
    // epilogue: T = (float*)sm, [512][68] f32 = 139264 B (SCL.. live beyond)

    const int bx = blockIdx.x;
    const int j8 = bx & 7;
    const int b = j8 >> 1;
    const int n0 = ((bx >> 3) + (j8 & 1) * 32) * 64;

    const size_t p16 = (size_t)CC * NN;
    const f16* __restrict__ Btb = Bt + (size_t)b * p16;   // [n][c]
    const f16* __restrict__ Ctb = Ct + (size_t)b * p16;   // [m][c]
    const f16* __restrict__ Dmb = Dm + (size_t)b * p16;   // [c][m]

    const int t = threadIdx.x;
    const int wid = t >> 6, lane = t & 63;
    const int l15 = lane & 15, g = lane >> 4;

    const bool isProd = (wid == 0) || (wid == 5);
    const bool isStg  = (wid == 1) || (wid == 4);
    const int  p  = (wid == 5) ? 1 : 0;               // producer index
    const int  u  = (wid == 4) ? 1 : 0;               // stager index
    const int  c4 = (wid < 4) ? (wid - 2) : (wid - 4); // consumer index (wid 2,3,6,7)

    f32x4 R[32];                               // producers: Q[2][16]; consumers: O[4][8]
    f32x4 m_run0 = (f32x4)(-INFINITY), m_run1 = (f32x4)(-INFINITY);
    f32x4 l_run0 = (f32x4)(0.f), l_run1 = (f32x4)(0.f);

    if (isProd) {
        const f16* q0 = Btb + (size_t)(n0 + p * 32 + l15) * CC + g * 8;
        const f16* q1 = q0 + (size_t)16 * CC;
        #pragma unroll
        for (int s = 0; s < 16; ++s) {
            R[s]      = __builtin_bit_cast(f32x4, *(const f16x8*)(q0 + s * 32));
            R[16 + s] = __builtin_bit_cast(f32x4, *(const f16x8*)(q1 + s * 32));
        }
    } else {
        #pragma unroll
        for (int i = 0; i < 32; ++i) R[i] = (f32x4)(0.f);
    }

    if (isStg) {                               // prologue: Ct(0) -> CtB[0]
        #pragma unroll
        for (int it = 0; it < 16; ++it) {
            int r = u * 16 + it;
            gload_lds16(Ctb + (size_t)r * CC + ((lane ^ (r & 7)) << 3), CtB + r * 512);
        }
    }
    __syncthreads();

    for (int i = 0; i <= 128; ++i) {
        const int cur = i & 1;
        if (isProd) {
            if (i < 128) {
                const f16* cb = CtB + cur * 16384;
                f32x4 S00 = (f32x4)(0.f), S01 = (f32x4)(0.f);
                f32x4 S10 = (f32x4)(0.f), S11 = (f32x4)(0.f);
                const int off7 = l15 & 7;
                __builtin_amdgcn_s_setprio(1);
                #pragma unroll
                for (int s = 0; s < 16; ++s) {
                    int sw = (((s * 4 + g) ^ off7) << 3);
                    f16x8 b0 = *(const f16x8*)(cb + l15 * 512 + sw);
                    f16x8 b1 = *(const f16x8*)(cb + (16 + l15) * 512 + sw);
                    f16x8 qa = __builtin_bit_cast(f16x8, R[s]);
                    f16x8 qb = __builtin_bit_cast(f16x8, R[16 + s]);
                    S00 = MFMA16(qa, b0, S00); S01 = MFMA16(qa, b1, S01);
                    S10 = MFMA16(qb, b0, S10); S11 = MFMA16(qb, b1, S11);
                }
                __builtin_amdgcn_s_setprio(0);
                f32x4 tm0, tm1;
                #pragma unroll
                for (int q = 0; q < 4; ++q) {
                    tm0[q] = fmaxf(S00[q], S01[q]);
                    tm1[q] = fmaxf(S10[q], S11[q]);
                }
                tm0 = rmax16(tm0); tm1 = rmax16(tm1);
                int grow = 0;
                #pragma unroll
                for (int q = 0; q < 4; ++q)
                    grow |= (tm0[q] > m_run0[q] + 8.f) | (tm1[q] > m_run1[q] + 8.f);
                const bool doR = __any(grow);
                f32x4 scl0 = (f32x4)(1.f), scl1 = (f32x4)(1.f);
                if (doR) {
                    #pragma unroll
                    for (int q = 0; q < 4; ++q) {
                        float mn = fmaxf(m_run0[q], tm0[q]);
                        scl0[q] = __expf(m_run0[q] - mn); m_run0[q] = mn;
                        mn = fmaxf(m_run1[q], tm1[q]);
                        scl1[q] = __expf(m_run1[q] - mn); m_run1[q] = mn;
                    }
                }
                #pragma unroll
                for (int q = 0; q < 4; ++q) {
                    S00[q] = __expf(S00[q] - m_run0[q]);
                    S01[q] = __expf(S01[q] - m_run0[q]);
                    S10[q] = __expf(S10[q] - m_run1[q]);
                    S11[q] = __expf(S11[q] - m_run1[q]);
                }
                f32x4 ps0, ps1;
                #pragma unroll
                for (int q = 0; q < 4; ++q) { ps0[q] = S00[q] + S01[q]; ps1[q] = S10[q] + S11[q]; }
                ps0 = rsum16(ps0); ps1 = rsum16(ps1);
                #pragma unroll
                for (int q = 0; q < 4; ++q) {
                    l_run0[q] = l_run0[q] * scl0[q] + ps0[q];
                    l_run1[q] = l_run1[q] * scl1[q] + ps1[q];
                }
                if (l15 == 0) {
                    *(f32x4*)(SCL + cur * 64 + p * 32 + g * 4) = scl0;
                    *(f32x4*)(SCL + cur * 64 + p * 32 + 16 + g * 4) = scl1;
                }
                if (lane == 0) FLG[cur * 2 + p] = doR ? 1 : 0;
                f16* pp = PSB + cur * 2048;
                const int posA = (((l15 >> 3) ^ g) << 3);
                const int posB = (((2 + (l15 >> 3)) ^ g) << 3);
                const int m7 = l15 & 7;
                #pragma unroll
                for (int q = 0; q < 4; ++q) {
                    int r0 = p * 32 + g * 4 + q;
                    int r1 = r0 + 16;
                    pp[r0 * 32 + posA + m7] = (f16)S00[q];
                    pp[r0 * 32 + posB + m7] = (f16)S01[q];
                    pp[r1 * 32 + posA + m7] = (f16)S10[q];
                    pp[r1 * 32 + posB + m7] = (f16)S11[q];
                }
            }
        } else if (isStg) {
            if (i + 1 < 128) {
                f16* db = CtB + (cur ^ 1) * 16384;
                const int m0n = (i + 1) * 32;
                #pragma unroll
                for (int it = 0; it < 16; ++it) {
                    int r = u * 16 + it;
                    gload_lds16(Ctb + (size_t)(m0n + r) * CC + ((lane ^ (r & 7)) << 3),
                                db + r * 512);
                }
            }
            if (i < 128) {
                f16* dd = DtB + cur * 16384;
                const int m0c = i * 32;
                #pragma unroll
                for (int it = 0; it < 16; ++it) {
                    int flatbase = (u * 16 + it) * 64;
                    int flat = flatbase + lane;
                    int r = flat >> 2, c4m = flat & 3;
                    gload_lds16(Dmb + (size_t)r * NN + m0c + (c4m << 3), dd + flatbase * 8);
                }
            }
        } else {
            if (i > 0) {
                const int prev = cur ^ 1;
                const f16* pp = PSB + prev * 2048;
                int fl = FLG[prev * 2] | FLG[prev * 2 + 1];
                if (fl) {
                    #pragma unroll
                    for (int na = 0; na < 4; ++na) {
                        f32x4 s4 = *(const f32x4*)(SCL + prev * 64 + na * 16 + g * 4);
                        #pragma unroll
                        for (int cb = 0; cb < 8; ++cb)
                            #pragma unroll
                            for (int q = 0; q < 4; ++q)
                                R[na * 8 + cb][q] *= s4[q];
                    }
                }
                f16x8 pa[4];
                #pragma unroll
                for (int na = 0; na < 4; ++na)
                    pa[na] = *(const f16x8*)(pp + (na * 16 + l15) * 32 +
                                             ((g ^ ((l15 >> 2) & 3)) << 3));
                f16x8 d[8];
                #pragma unroll
                for (int cb = 0; cb < 8; ++cb)
                    d[cb] = *(const f16x8*)(DtB + prev * 16384 +
                                            (c4 * 128 + cb * 16 + l15) * 32 + (g << 3));
                __builtin_amdgcn_s_setprio(1);
                #pragma unroll
                for (int na = 0; na < 4; ++na)
                    #pragma unroll
                    for (int cb = 0; cb < 8; ++cb)
                        R[na * 8 + cb] = MFMA16(pa[na], d[cb], R[na * 8 + cb]);
                __builtin_amdgcn_s_setprio(0);
            }
        }
        __syncthreads();
    }

    // ---- epilogue ----
    if (isProd && l15 == 0) {
        *(f32x4*)(LROW + p * 32 + g * 4) = l_run0;
        *(f32x4*)(LROW + p * 32 + 16 + g * 4) = l_run1;
    }
    __syncthreads();
    const float gam = gamma_p[0];
    float* T = (float*)sm;                     // [512][68] f32
    if (!isProd && !isStg) {
        #pragma unroll
        for (int na = 0; na < 4; ++na) {
            f32x4 lr = *(const f32x4*)(LROW + na * 16 + g * 4);
            f32x4 inv;
            #pragma unroll
            for (int q = 0; q < 4; ++q) inv[q] = gam / lr[q];
            #pragma unroll
            for (int cb = 0; cb < 8; ++cb) {
                int c = c4 * 128 + cb * 16 + l15;
                f32x4 v;
                #pragma unroll
                for (int q = 0; q < 4; ++q) v[q] = R[na * 8 + cb][q] * inv[q];
                *(f32x4*)(T + c * 68 + na * 16 + g * 4) = v;
            }
        }
    }
    __syncthreads();
    const float* __restrict__ xb = x + (size_t)b * CC * NN;
    float* __restrict__ ob = out + (size_t)b * CC * NN;
    #pragma unroll
    for (int it = 0; it < 16; ++it) {
        int c = (t >> 4) + it * 32;
        int n4 = (t & 15) * 4;
        f32x4 v = *(const f32x4*)(T + c * 68 + n4);
        f32x4 xv = *(const f32x4*)(xb + (size_t)c * NN + n0 + n4);
        #pragma unroll
        for (int q = 0; q < 4; ++q) v[q] += xv[q];
        *(f32x4*)(ob + (size_t)c * NN + n0 + n4) = v;
    }
}

extern "C" void kernel_launch(void* const* d_in, const int* in_sizes, int n_in,
                              void* d_out, int out_size, void* d_ws, size_t ws_size,
                              hipStream_t stream) {
    const float* x  = (const float*)d_in[0];
    const float* Wb = (const float*)d_in[1];
    const float* Wc = (const float*)d_in[2];
    const float* Wd = (const float*)d_in[3];
    const float* gm = (const float*)d_in[4];
    float* out = (float*)d_out;
    char* ws = (char*)d_ws;

    // ws: W16 1.5MB | Bt 16MB | Ct 16MB | Dm 16MB  (~49.5MB)
    f16* W16 = (f16*)(ws);
    f16* Bt  = (f16*)(ws + 1572864);
    f16* Ct  = (f16*)(ws + 1572864 + 16777216);
    f16* Dm  = (f16*)(ws + 1572864 + 2 * 16777216);

    wcvt_k<<<dim3(768), 256, 0, stream>>>(Wb, Wc, Wd, W16);
    proj_k<<<dim3(32, 4, 12), 256, 0, stream>>>(x, W16, Bt, Ct, Dm);
    flash_k<<<dim3(256), 512, 0, stream>>>(x, gm, Bt, Ct, Dm, out);
}

// Round 13
// 465.944 us; speedup vs baseline: 7.1505x; 7.1505x over previous
//
#include <hip/hip_runtime.h>
#include <math.h>
#include <stdint.h>

#define CC 512
#define NN 4096
#define BB 4

typedef _Float16 f16;
typedef _Float16 f16x8 __attribute__((ext_vector_type(8)));
typedef _Float16 f16x4 __attribute__((ext_vector_type(4)));
typedef float f32x4 __attribute__((ext_vector_type(4)));

// ---------- async global->LDS 16B ----------
__device__ __forceinline__ void gload_lds16(const void* g, void* l) {
    __builtin_amdgcn_global_load_lds(
        (const __attribute__((address_space(1))) void*)g,
        (__attribute__((address_space(3))) void*)l, 16, 0, 0);
}

// Stage ROWS rows x 64 f16 from K-major global into linear LDS; source pre-swizzled.
template<int ROWS>
__device__ __forceinline__ void stage_tile(const f16* __restrict__ g, int stride_e,
                                           f16* lds, int wid, int lane) {
    constexpr int ITERS = ROWS * 8 / 64 / 4;   // 4 waves
    #pragma unroll
    for (int it = 0; it < ITERS; ++it) {
        int flatbase = (wid * ITERS + it) * 64;
        f16* dst = lds + flatbase * 8;
        int flat = flatbase + lane;
        int r = flat >> 3, c = flat & 7;
        const f16* src = g + (size_t)r * stride_e + ((c ^ (r & 7)) << 3);
        gload_lds16(src, dst);
    }
}

__device__ __forceinline__ f16x8 frag_ld(const f16* lds, int r, int ch) {
    return *(const f16x8*)(lds + r * 64 + ((ch ^ (r & 7)) << 3));
}

#define MFMA16(a, b, c) __builtin_amdgcn_mfma_f32_16x16x32_f16((a), (b), (c), 0, 0, 0)

// ---------- DPP row_ror reductions over 16-lane rows (VALU only) ----------
template<int N>
__device__ __forceinline__ float ror16(float x) {
    return __int_as_float(__builtin_amdgcn_update_dpp(
        0, __float_as_int(x), 0x120 + N, 0xF, 0xF, true));
}
__device__ __forceinline__ f32x4 rmax16(f32x4 v) {
    #pragma unroll
    for (int q = 0; q < 4; ++q) {
        float x = v[q];
        x = fmaxf(x, ror16<1>(x));
        x = fmaxf(x, ror16<2>(x));
        x = fmaxf(x, ror16<4>(x));
        x = fmaxf(x, ror16<8>(x));
        v[q] = x;
    }
    return v;
}
__device__ __forceinline__ f32x4 rsum16(f32x4 v) {
    #pragma unroll
    for (int q = 0; q < 4; ++q) {
        float x = v[q];
        x += ror16<1>(x);
        x += ror16<2>(x);
        x += ror16<4>(x);
        x += ror16<8>(x);
        v[q] = x;
    }
    return v;
}

// ---------------- W conversion ----------------
__global__ __launch_bounds__(256) void wcvt_k(const float* __restrict__ Wb,
                                              const float* __restrict__ Wc,
                                              const float* __restrict__ Wd,
                                              f16* __restrict__ W16) {
    int i = blockIdx.x * 256 + threadIdx.x;
    int idx = i * 4;
    int m = idx >> 18;
    int off = idx & 262143;
    const float* src = (m == 0) ? Wb : (m == 1) ? Wc : Wd;
    f32x4 v = *(const f32x4*)(src + off);
    f16x4 h = { (f16)v[0], (f16)v[1], (f16)v[2], (f16)v[3] };
    *(f16x4*)(W16 + idx) = h;
}

// ---------------- proj (all batches): O = W @ x ----------------
__global__ __launch_bounds__(256) void proj_k(const float* __restrict__ x,
                                              const f16* __restrict__ W16,
                                              f16* __restrict__ Bt, f16* __restrict__ Ct,
                                              f16* __restrict__ Dm) {
    const int wsel = blockIdx.z % 3;
    const int b = blockIdx.z / 3;
    const f16* __restrict__ W = W16 + (size_t)wsel * CC * CC;
    const float* __restrict__ X = x + (size_t)b * CC * NN;
    const size_t p16 = (size_t)CC * NN;
    const int o0 = blockIdx.y * 128, n0 = blockIdx.x * 128;

    __shared__ __align__(16) char smraw[34816];
    f16* As = (f16*)smraw;
    f16* Bs = As + 128 * 64;
    f16* T  = (f16*)smraw;

    const int t = threadIdx.x;
    const int wid = t >> 6, lane = t & 63;
    const int wr = wid >> 1, wc = wid & 1;

    f32x4 acc[4][4] = {};
    const int cg = t & 7;
    const int n4 = ((t >> 3) & 31) * 4;

    for (int kc = 0; kc < CC; kc += 64) {
        __syncthreads();
        stage_tile<128>(W + (size_t)o0 * CC + kc, CC, As, wid, lane);
        f32x4 v[8];
        #pragma unroll
        for (int i = 0; i < 8; ++i)
            v[i] = *(const f32x4*)(X + (size_t)(kc + cg * 8 + i) * NN + n0 + n4);
        #pragma unroll
        for (int j = 0; j < 4; ++j) {
            f16x8 h = { (f16)v[0][j], (f16)v[1][j], (f16)v[2][j], (f16)v[3][j],
                        (f16)v[4][j], (f16)v[5][j], (f16)v[6][j], (f16)v[7][j] };
            int r = n4 + j;
            *(f16x8*)(Bs + r * 64 + ((cg ^ (r & 7)) << 3)) = h;
        }
        __syncthreads();
        #pragma unroll
        for (int ks = 0; ks < 2; ++ks) {
            int ch = ks * 4 + (lane >> 4);
            f16x8 a[4], bb[4];
            #pragma unroll
            for (int i = 0; i < 4; ++i) a[i]  = frag_ld(As, wr * 64 + i * 16 + (lane & 15), ch);
            #pragma unroll
            for (int j = 0; j < 4; ++j) bb[j] = frag_ld(Bs, wc * 64 + j * 16 + (lane & 15), ch);
            #pragma unroll
            for (int i = 0; i < 4; ++i)
                #pragma unroll
                for (int j = 0; j < 4; ++j)
                    acc[i][j] = MFMA16(a[i], bb[j], acc[i][j]);
        }
    }

    __syncthreads();
    if (wsel < 2) {
        #pragma unroll
        for (int i = 0; i < 4; ++i)
            #pragma unroll
            for (int j = 0; j < 4; ++j) {
                int n_l = wc * 64 + j * 16 + (lane & 15);
                int o_l = wr * 64 + i * 16 + (lane >> 4) * 4;
                f16x4 h = { (f16)acc[i][j][0], (f16)acc[i][j][1], (f16)acc[i][j][2], (f16)acc[i][j][3] };
                *(f16x4*)(T + n_l * 136 + o_l) = h;
            }
        __syncthreads();
        f16* __restrict__ dst = ((wsel == 0) ? Bt : Ct) + (size_t)b * p16;
        int n = t & 127;
        #pragma unroll
        for (int it = 0; it < 8; ++it) {
            int ch8 = (t >> 7) * 8 + it;
            f16x8 h = *(f16x8*)(T + n * 136 + ch8 * 8);
            *(f16x8*)(dst + (size_t)(n0 + n) * CC + o0 + ch8 * 8) = h;
        }
    } else {
        #pragma unroll
        for (int i = 0; i < 4; ++i)
            #pragma unroll
            for (int j = 0; j < 4; ++j) {
                int n_l = wc * 64 + j * 16 + (lane & 15);
                #pragma unroll
                for (int q = 0; q < 4; ++q) {
                    int o_l = wr * 64 + i * 16 + (lane >> 4) * 4 + q;
                    T[o_l * 136 + n_l] = (f16)acc[i][j][q];
                }
            }
        __syncthreads();
        f16* __restrict__ dst = Dm + (size_t)b * p16;
        int o = t & 127;
        #pragma unroll
        for (int it = 0; it < 8; ++it) {
            int ch8 = (t >> 7) * 8 + it;
            f16x8 h = *(f16x8*)(T + o * 136 + ch8 * 8);
            *(f16x8*)(dst + (size_t)(o0 + o) * NN + n0 + ch8 * 8) = h;
        }
    }
}

// ---------- flash staging (32-m tiles) ----------
__device__ __forceinline__ void stage_Ct32(const f16* __restrict__ Ctb, f16* dstbase,
                                           int m0, int w4, int lane) {
    #pragma unroll
    for (int it = 0; it < 8; ++it) {
        int flatbase = (w4 * 8 + it) * 64;
        f16* dst = dstbase + flatbase * 8;
        int r = flatbase >> 6;                // uniform: w4*8+it
        const f16* src = Ctb + (size_t)(m0 + r) * CC + ((lane ^ (r & 7)) << 3);
        gload_lds16(src, dst);
    }
}
// DtB tile [512 c][32 m], LINEAR. Wave w4 stages exactly rows [w4*128,(w4+1)*128)
// == the rows it reads in PV (self-consumed -> counted vmcnt, no barrier needed).
__device__ __forceinline__ void stage_Dt32(const f16* __restrict__ Dmb, f16* DtB,
                                           int m0, int w4, int lane) {
    #pragma unroll
    for (int it = 0; it < 8; ++it) {
        int flatbase = (w4 * 8 + it) * 64;
        f16* dst = DtB + flatbase * 8;
        int flat = flatbase + lane;
        int r = flat >> 2, c4 = flat & 3;
        const f16* src = Dmb + (size_t)r * NN + m0 + (c4 << 3);
        gload_lds16(src, dst);
    }
}

// ---------------- fused flash attention: r10 roles + counted-vmcnt pipeline ----------------
// Waves 0-3 producers (QK+softmax, 16 n-rows each, Q[16] regs — proven no-spill 322us),
// waves 4-7 consumers (PV, O=64nx128c). Changes vs r10 (T3/T4):
//  * Dt DOUBLE-buffered, issued at consumer-iter TOP -> full-iter latency cover; the
//    in-flight loads RIDE ACROSS the raw s_barrier (self-consumed; vmcnt(8) at next use).
//  * raw s_barrier instead of __syncthreads: producers drain lgkm(0)+vm(0) (near-free,
//    full-iter cover on their 1-ahead Ct prefetch); consumers never drain at barrier.
__global__ __launch_bounds__(512) void flash_k(
    const float* __restrict__ x, const float* __restrict__ gamma_p,
    const f16* __restrict__ Bt, const f16* __restrict__ Ct,
    const f16* __restrict__ Dm, float* __restrict__ out)
{
    __shared__ __align__(16) char sm[140032];
    f16*   CtB  = (f16*)sm;                    // [2][32][512]  65536 B
    f16*   DtB  = (f16*)(sm + 65536);          // [2][512][32]  65536 B
    f16*   PSB  = (f16*)(sm + 131072);         // [2][64][32]    8192 B
    float* SCL  = (float*)(sm + 139264);       // [2][64]         512 B
    float* LROW = (float*)(sm + 139776);       // [64]            256 B (beyond T)
    // epilogue: T = (float*)sm, [512][68] f32 = 139264 B

    const int bx = blockIdx.x;
    const int j8 = bx & 7;
    const int b = j8 >> 1;
    const int n0 = ((bx >> 3) + (j8 & 1) * 32) * 64;

    const size_t p16 = (size_t)CC * NN;
    const f16* __restrict__ Btb = Bt + (size_t)b * p16;   // [n][c]
    const f16* __restrict__ Ctb = Ct + (size_t)b * p16;   // [m][c]
    const f16* __restrict__ Dmb = Dm + (size_t)b * p16;   // [c][m]

    const int t = threadIdx.x;
    const int wid = t >> 6, lane = t & 63;
    const int w4 = wid & 3;
    const bool isP = wid < 4;
    const int l15 = lane & 15, g = lane >> 4;

    f32x4 R[32];                               // producers: Q[16] (R[0..15]); consumers: O[4][8]
    f32x4 m_run = (f32x4)(-INFINITY);
    f32x4 l_run = (f32x4)(0.f);

    if (isP) {
        const f16* qrow = Btb + (size_t)(n0 + w4 * 16 + l15) * CC + g * 8;
        #pragma unroll
        for (int s = 0; s < 16; ++s)
            R[s] = __builtin_bit_cast(f32x4, *(const f16x8*)(qrow + s * 32));
    } else {
        #pragma unroll
        for (int i = 0; i < 32; ++i) R[i] = (f32x4)(0.f);
    }

    if (isP) {
        stage_Ct32(Ctb, CtB, 0, w4, lane);
        asm volatile("s_waitcnt vmcnt(0)" ::: "memory");
    }
    __builtin_amdgcn_sched_barrier(0);
    __builtin_amdgcn_s_barrier();
    __builtin_amdgcn_sched_barrier(0);

    for (int i = 0; i <= 128; ++i) {
        const int cur = i & 1;
        if (isP) {
            if (i < 128) {
                // 1-ahead Ct prefetch into the buffer NOT read this iter
                if (i + 1 < 128)
                    stage_Ct32(Ctb, CtB + (cur ^ 1) * 16384, (i + 1) * 32, w4, lane);
                // ---- QK(i): 16n x 32m per wave ----
                f32x4 S0 = (f32x4)(0.f), S1 = (f32x4)(0.f);
                const f16* cb = CtB + cur * 16384;
                __builtin_amdgcn_s_setprio(1);
                #pragma unroll
                for (int s = 0; s < 16; ++s) {
                    int ch = s * 4 + g;
                    f16x8 b0 = *(const f16x8*)(cb + l15 * 512 + ((ch ^ (l15 & 7)) << 3));
                    f16x8 b1 = *(const f16x8*)(cb + (16 + l15) * 512 + ((ch ^ (l15 & 7)) << 3));
                    f16x8 q = __builtin_bit_cast(f16x8, R[s]);
                    S0 = MFMA16(q, b0, S0);
                    S1 = MFMA16(q, b1, S1);
                }
                __builtin_amdgcn_s_setprio(0);
                // ---- wave-local softmax (rows w4*16 + g*4 + q) ----
                f32x4 tm, scl;
                #pragma unroll
                for (int q = 0; q < 4; ++q) tm[q] = fmaxf(S0[q], S1[q]);
                tm = rmax16(tm);
                #pragma unroll
                for (int q = 0; q < 4; ++q) {
                    float mnew = fmaxf(m_run[q], tm[q]);
                    scl[q] = __expf(m_run[q] - mnew);
                    m_run[q] = mnew;
                    S0[q] = __expf(S0[q] - mnew);
                    S1[q] = __expf(S1[q] - mnew);
                }
                f32x4 ps;
                #pragma unroll
                for (int q = 0; q < 4; ++q) ps[q] = S0[q] + S1[q];
                ps = rsum16(ps);
                #pragma unroll
                for (int q = 0; q < 4; ++q) l_run[q] = l_run[q] * scl[q] + ps[q];
                if (l15 == 0) *(f32x4*)(SCL + cur * 64 + w4 * 16 + g * 4) = scl;
                // P write, chunk-swizzled
                f16* pp = PSB + cur * 2048;
                #pragma unroll
                for (int q = 0; q < 4; ++q) {
                    int row = w4 * 16 + g * 4 + q;
                    pp[row * 32 + ((((l15 >> 3) ^ g) << 3) | (l15 & 7))] = (f16)S0[q];
                    pp[row * 32 + ((((2 + (l15 >> 3)) ^ g) << 3) | (l15 & 7))] = (f16)S1[q];
                }
                // publish: LDS writes + this iter's Ct prefetch (full-iter cover -> cheap)
                asm volatile("s_waitcnt lgkmcnt(0)" ::: "memory");
                asm volatile("s_waitcnt vmcnt(0)" ::: "memory");
            }
        } else {
            // issue Dt(i) FIRST into buf[cur] (PV below reads buf[cur^1]) — loads
            // stay in flight across the barrier; consumed next iter via vmcnt(8)
            if (i < 128) stage_Dt32(Dmb, DtB + cur * 16384, i * 32, w4, lane);
            if (i > 0) {
                if (i < 128) asm volatile("s_waitcnt vmcnt(8)" ::: "memory");
                else         asm volatile("s_waitcnt vmcnt(0)" ::: "memory");
                __builtin_amdgcn_sched_barrier(0);
                // ---- PV(i-1): 64n x 128c per wave ----
                const int prev = cur ^ 1;
                const f16* pp = PSB + prev * 2048;
                const float* sc = SCL + prev * 64;
                f32x4 scl4[4];
                #pragma unroll
                for (int na = 0; na < 4; ++na)
                    scl4[na] = *(const f32x4*)(sc + na * 16 + g * 4);
                #pragma unroll
                for (int na = 0; na < 4; ++na)
                    #pragma unroll
                    for (int cb = 0; cb < 8; ++cb)
                        #pragma unroll
                        for (int q = 0; q < 4; ++q)
                            R[na * 8 + cb][q] *= scl4[na][q];
                f16x8 pa[4];
                #pragma unroll
                for (int na = 0; na < 4; ++na) {
                    int row = na * 16 + l15;
                    pa[na] = *(const f16x8*)(pp + row * 32 + ((g ^ (l15 >> 2)) << 3));
                }
                f16x8 d[8];
                #pragma unroll
                for (int cb = 0; cb < 8; ++cb)
                    d[cb] = *(const f16x8*)(DtB + prev * 16384 +
                                            (w4 * 128 + cb * 16 + l15) * 32 + (g << 3));
                __builtin_amdgcn_s_setprio(1);
                #pragma unroll
                for (int na = 0; na < 4; ++na)
                    #pragma unroll
                    for (int cb = 0; cb < 8; ++cb)
                        R[na * 8 + cb] = MFMA16(pa[na], d[cb], R[na * 8 + cb]);
                __builtin_amdgcn_s_setprio(0);
            }
        }
        __builtin_amdgcn_sched_barrier(0);
        __builtin_amdgcn_s_barrier();
        __builtin_amdgcn_sched_barrier(0);
    }

    // ---- epilogue ----
    if (isP && l15 == 0) *(f32x4*)(LROW + w4 * 16 + g * 4) = l_run;
    __syncthreads();
    const float gam = gamma_p[0];
    float* T = (float*)sm;                     // [512][68] f32 (LROW beyond)
    if (!isP) {
        #pragma unroll
        for (int na = 0; na < 4; ++na) {
            f32x4 lr = *(const f32x4*)(LROW + na * 16 + g * 4);
            f32x4 inv;
            #pragma unroll
            for (int q = 0; q < 4; ++q) inv[q] = gam / lr[q];
            #pragma unroll
            for (int cb = 0; cb < 8; ++cb) {
                int c = w4 * 128 + cb * 16 + l15;
                f32x4 v;
                #pragma unroll
                for (int q = 0; q < 4; ++q) v[q] = R[na * 8 + cb][q] * inv[q];
                *(f32x4*)(T + c * 68 + na * 16 + g * 4) = v;
            }
        }
    }
    __syncthreads();
    const float* __restrict__ xb = x + (size_t)b * CC * NN;
    float* __restrict__ ob = out + (size_t)b * CC * NN;
    #pragma unroll
    for (int it = 0; it < 16; ++it) {
        int c = (t >> 4) + it * 32;
        int n4 = (t & 15) * 4;
        f32x4 v = *(const f32x4*)(T + c * 68 + n4);
        f32x4 xv = *(const f32x4*)(xb + (size_t)c * NN + n0 + n4);
        #pragma unroll
        for (int q = 0; q < 4; ++q) v[q] += xv[q];
        *(f32x4*)(ob + (size_t)c * NN + n0 + n4) = v;
    }
}

extern "C" void kernel_launch(void* const* d_in, const int* in_sizes, int n_in,
                              void* d_out, int out_size, void* d_ws, size_t ws_size,
                              hipStream_t stream) {
    const float* x  = (const float*)d_in[0];
    const float* Wb = (const float*)d_in[1];
    const float* Wc = (const float*)d_in[2];
    const float* Wd = (const float*)d_in[3];
    const float* gm = (const float*)d_in[4];
    float* out = (float*)d_out;
    char* ws = (char*)d_ws;

    // ws: W16 1.5MB | Bt 16MB | Ct 16MB | Dm 16MB  (~49.5MB)
    f16* W16 = (f16*)(ws);
    f16* Bt  = (f16*)(ws + 1572864);
    f16* Ct  = (f16*)(ws + 1572864 + 16777216);
    f16* Dm  = (f16*)(ws + 1572864 + 2 * 16777216);

    wcvt_k<<<dim3(768), 256, 0, stream>>>(Wb, Wc, Wd, W16);
    proj_k<<<dim3(32, 4, 12), 256, 0, stream>>>(x, W16, Bt, Ct, Dm);
    flash_k<<<dim3(256), 512, 0, stream>>>(x, gm, Bt, Ct, Dm, out);
}

// Round 14
// 377.633 us; speedup vs baseline: 8.8227x; 1.2339x over previous
//
#include <hip/hip_runtime.h>
#include <math.h>
#include <stdint.h>

#define CC 512
#define NN 4096
#define BB 4

typedef _Float16 f16;
typedef _Float16 f16x8 __attribute__((ext_vector_type(8)));
typedef _Float16 f16x4 __attribute__((ext_vector_type(4)));
typedef float f32x4 __attribute__((ext_vector_type(4)));

// ---------- async global->LDS 16B ----------
__device__ __forceinline__ void gload_lds16(const void* g, void* l) {
    __builtin_amdgcn_global_load_lds(
        (const __attribute__((address_space(1))) void*)g,
        (__attribute__((address_space(3))) void*)l, 16, 0, 0);
}

// Stage ROWS rows x 64 f16 from K-major global into linear LDS; source pre-swizzled.
template<int ROWS>
__device__ __forceinline__ void stage_tile(const f16* __restrict__ g, int stride_e,
                                           f16* lds, int wid, int lane) {
    constexpr int ITERS = ROWS * 8 / 64 / 4;   // 4 waves
    #pragma unroll
    for (int it = 0; it < ITERS; ++it) {
        int flatbase = (wid * ITERS + it) * 64;
        f16* dst = lds + flatbase * 8;
        int flat = flatbase + lane;
        int r = flat >> 3, c = flat & 7;
        const f16* src = g + (size_t)r * stride_e + ((c ^ (r & 7)) << 3);
        gload_lds16(src, dst);
    }
}

__device__ __forceinline__ f16x8 frag_ld(const f16* lds, int r, int ch) {
    return *(const f16x8*)(lds + r * 64 + ((ch ^ (r & 7)) << 3));
}

#define MFMA16(a, b, c) __builtin_amdgcn_mfma_f32_16x16x32_f16((a), (b), (c), 0, 0, 0)

// ---------- DPP row_ror reductions over 16-lane rows (VALU only) ----------
template<int N>
__device__ __forceinline__ float ror16(float x) {
    return __int_as_float(__builtin_amdgcn_update_dpp(
        0, __float_as_int(x), 0x120 + N, 0xF, 0xF, true));
}
__device__ __forceinline__ f32x4 rmax16(f32x4 v) {
    #pragma unroll
    for (int q = 0; q < 4; ++q) {
        float x = v[q];
        x = fmaxf(x, ror16<1>(x));
        x = fmaxf(x, ror16<2>(x));
        x = fmaxf(x, ror16<4>(x));
        x = fmaxf(x, ror16<8>(x));
        v[q] = x;
    }
    return v;
}
__device__ __forceinline__ f32x4 rsum16(f32x4 v) {
    #pragma unroll
    for (int q = 0; q < 4; ++q) {
        float x = v[q];
        x += ror16<1>(x);
        x += ror16<2>(x);
        x += ror16<4>(x);
        x += ror16<8>(x);
        v[q] = x;
    }
    return v;
}

// ---------------- W conversion ----------------
__global__ __launch_bounds__(256) void wcvt_k(const float* __restrict__ Wb,
                                              const float* __restrict__ Wc,
                                              const float* __restrict__ Wd,
                                              f16* __restrict__ W16) {
    int i = blockIdx.x * 256 + threadIdx.x;
    int idx = i * 4;
    int m = idx >> 18;
    int off = idx & 262143;
    const float* src = (m == 0) ? Wb : (m == 1) ? Wc : Wd;
    f32x4 v = *(const f32x4*)(src + off);
    f16x4 h = { (f16)v[0], (f16)v[1], (f16)v[2], (f16)v[3] };
    *(f16x4*)(W16 + idx) = h;
}

// ---------------- proj (all batches): O = W @ x ----------------
__global__ __launch_bounds__(256) void proj_k(const float* __restrict__ x,
                                              const f16* __restrict__ W16,
                                              f16* __restrict__ Bt, f16* __restrict__ Ct,
                                              f16* __restrict__ Dm) {
    const int wsel = blockIdx.z % 3;
    const int b = blockIdx.z / 3;
    const f16* __restrict__ W = W16 + (size_t)wsel * CC * CC;
    const float* __restrict__ X = x + (size_t)b * CC * NN;
    const size_t p16 = (size_t)CC * NN;
    const int o0 = blockIdx.y * 128, n0 = blockIdx.x * 128;

    __shared__ __align__(16) char smraw[34816];
    f16* As = (f16*)smraw;
    f16* Bs = As + 128 * 64;
    f16* T  = (f16*)smraw;

    const int t = threadIdx.x;
    const int wid = t >> 6, lane = t & 63;
    const int wr = wid >> 1, wc = wid & 1;

    f32x4 acc[4][4] = {};
    const int cg = t & 7;
    const int n4 = ((t >> 3) & 31) * 4;

    for (int kc = 0; kc < CC; kc += 64) {
        __syncthreads();
        stage_tile<128>(W + (size_t)o0 * CC + kc, CC, As, wid, lane);
        f32x4 v[8];
        #pragma unroll
        for (int i = 0; i < 8; ++i)
            v[i] = *(const f32x4*)(X + (size_t)(kc + cg * 8 + i) * NN + n0 + n4);
        #pragma unroll
        for (int j = 0; j < 4; ++j) {
            f16x8 h = { (f16)v[0][j], (f16)v[1][j], (f16)v[2][j], (f16)v[3][j],
                        (f16)v[4][j], (f16)v[5][j], (f16)v[6][j], (f16)v[7][j] };
            int r = n4 + j;
            *(f16x8*)(Bs + r * 64 + ((cg ^ (r & 7)) << 3)) = h;
        }
        __syncthreads();
        #pragma unroll
        for (int ks = 0; ks < 2; ++ks) {
            int ch = ks * 4 + (lane >> 4);
            f16x8 a[4], bb[4];
            #pragma unroll
            for (int i = 0; i < 4; ++i) a[i]  = frag_ld(As, wr * 64 + i * 16 + (lane & 15), ch);
            #pragma unroll
            for (int j = 0; j < 4; ++j) bb[j] = frag_ld(Bs, wc * 64 + j * 16 + (lane & 15), ch);
            #pragma unroll
            for (int i = 0; i < 4; ++i)
                #pragma unroll
                for (int j = 0; j < 4; ++j)
                    acc[i][j] = MFMA16(a[i], bb[j], acc[i][j]);
        }
    }

    __syncthreads();
    if (wsel < 2) {
        #pragma unroll
        for (int i = 0; i < 4; ++i)
            #pragma unroll
            for (int j = 0; j < 4; ++j) {
                int n_l = wc * 64 + j * 16 + (lane & 15);
                int o_l = wr * 64 + i * 16 + (lane >> 4) * 4;
                f16x4 h = { (f16)acc[i][j][0], (f16)acc[i][j][1], (f16)acc[i][j][2], (f16)acc[i][j][3] };
                *(f16x4*)(T + n_l * 136 + o_l) = h;
            }
        __syncthreads();
        f16* __restrict__ dst = ((wsel == 0) ? Bt : Ct) + (size_t)b * p16;
        int n = t & 127;
        #pragma unroll
        for (int it = 0; it < 8; ++it) {
            int ch8 = (t >> 7) * 8 + it;
            f16x8 h = *(f16x8*)(T + n * 136 + ch8 * 8);
            *(f16x8*)(dst + (size_t)(n0 + n) * CC + o0 + ch8 * 8) = h;
        }
    } else {
        #pragma unroll
        for (int i = 0; i < 4; ++i)
            #pragma unroll
            for (int j = 0; j < 4; ++j) {
                int n_l = wc * 64 + j * 16 + (lane & 15);
                #pragma unroll
                for (int q = 0; q < 4; ++q) {
                    int o_l = wr * 64 + i * 16 + (lane >> 4) * 4 + q;
                    T[o_l * 136 + n_l] = (f16)acc[i][j][q];
                }
            }
        __syncthreads();
        f16* __restrict__ dst = Dm + (size_t)b * p16;
        int o = t & 127;
        #pragma unroll
        for (int it = 0; it < 8; ++it) {
            int ch8 = (t >> 7) * 8 + it;
            f16x8 h = *(f16x8*)(T + o * 136 + ch8 * 8);
            *(f16x8*)(dst + (size_t)(o0 + o) * NN + n0 + ch8 * 8) = h;
        }
    }
}

// ---------- flash staging (32-m tiles) ----------
__device__ __forceinline__ void stage_Ct32(const f16* __restrict__ Ctb, f16* dstbase,
                                           int m0, int w4, int lane) {
    #pragma unroll
    for (int it = 0; it < 8; ++it) {
        int flatbase = (w4 * 8 + it) * 64;
        f16* dst = dstbase + flatbase * 8;
        int r = flatbase >> 6;                // uniform: w4*8+it
        const f16* src = Ctb + (size_t)(m0 + r) * CC + ((lane ^ (r & 7)) << 3);
        gload_lds16(src, dst);
    }
}
// DtB tile [512 c][32 m], LINEAR. Wave w4 stages exactly rows [w4*128,(w4+1)*128)
// == the rows it reads in PV.
__device__ __forceinline__ void stage_Dt32(const f16* __restrict__ Dmb, f16* DtB,
                                           int m0, int w4, int lane) {
    #pragma unroll
    for (int it = 0; it < 8; ++it) {
        int flatbase = (w4 * 8 + it) * 64;
        f16* dst = DtB + flatbase * 8;
        int flat = flatbase + lane;
        int r = flat >> 2, c4 = flat & 3;
        const f16* src = Dmb + (size_t)r * NN + m0 + (c4 << 3);
        gload_lds16(src, dst);
    }
}

// ---------------- fused flash attention: r10 + Dt double-buffer (issue-early) ----------------
// EXACT r10 structure (proven 322us flash, no spill): waves 0-3 producers (QK+softmax,
// 16 n-rows each, Q[16] regs), waves 4-7 consumers (PV, O=64nx128c), __syncthreads/iter.
// ONE change (T14): Dt double-buffered and staged at consumer-iter TOP (before PV) —
// Dt(i) -> DtB[i&1] while PV(i-1) reads DtB[(i-1)&1]. The iter-ending __syncthreads'
// implicit vmcnt(0) drain now has PV's MFMA as latency cover (r10 restaged AFTER PV
// into the same buffer -> ~L2 latency exposed at every barrier with zero cover).
__global__ __launch_bounds__(512) void flash_k(
    const float* __restrict__ x, const float* __restrict__ gamma_p,
    const f16* __restrict__ Bt, const f16* __restrict__ Ct,
    const f16* __restrict__ Dm, float* __restrict__ out)
{
    __shared__ __align__(16) char sm[140032];
    f16*   CtB  = (f16*)sm;                    // [2][32][512]  65536 B
    f16*   DtB  = (f16*)(sm + 65536);          // [2][512][32]  65536 B
    f16*   PSB  = (f16*)(sm + 131072);         // [2][64][32]    8192 B (chunk^g swizzled)
    float* SCL  = (float*)(sm + 139264);       // [2][64]         512 B
    float* LROW = (float*)(sm + 139776);       // [64]            256 B (beyond T)
    // epilogue: T = (float*)sm, [512][68] f32 = 139264 B

    // XCD-pair swizzle: 256 blocks
    const int bx = blockIdx.x;
    const int j8 = bx & 7;
    const int b = j8 >> 1;
    const int n0 = ((bx >> 3) + (j8 & 1) * 32) * 64;

    const size_t p16 = (size_t)CC * NN;
    const f16* __restrict__ Btb = Bt + (size_t)b * p16;   // [n][c]
    const f16* __restrict__ Ctb = Ct + (size_t)b * p16;   // [m][c]
    const f16* __restrict__ Dmb = Dm + (size_t)b * p16;   // [c][m]

    const int t = threadIdx.x;
    const int wid = t >> 6, lane = t & 63;
    const int w4 = wid & 3;
    const bool isP = wid < 4;                  // producer gang
    const int l15 = lane & 15, g = lane >> 4;

    f32x4 R[32];                               // producer: R[0..15] = Q; consumer: O[4][8]
    f32x4 m_run = (f32x4)(-INFINITY);
    f32x4 l_run = (f32x4)(0.f);

    if (isP) {
        const f16* qrow = Btb + (size_t)(n0 + w4 * 16 + l15) * CC + g * 8;
        #pragma unroll
        for (int s = 0; s < 16; ++s)
            R[s] = __builtin_bit_cast(f32x4, *(const f16x8*)(qrow + s * 32));
    } else {
        #pragma unroll
        for (int i = 0; i < 32; ++i) R[i] = (f32x4)(0.f);
    }

    if (isP) stage_Ct32(Ctb, CtB, 0, w4, lane);
    __syncthreads();

    for (int i = 0; i < 128; ++i) {
        const int cur = i & 1;
        if (isP) {
            // prefetch Ct(i+1) into other buffer (lands during this iter)
            if (i + 1 < 128) stage_Ct32(Ctb, CtB + (cur ^ 1) * 16384, (i + 1) * 32, w4, lane);
            // ---- QK(i): 16n x 32m per wave ----
            f32x4 S0 = (f32x4)(0.f), S1 = (f32x4)(0.f);
            const f16* cb = CtB + cur * 16384;
            __builtin_amdgcn_s_setprio(1);
            #pragma unroll
            for (int s = 0; s < 16; ++s) {
                int ch = s * 4 + g;
                f16x8 b0 = *(const f16x8*)(cb + l15 * 512 + ((ch ^ (l15 & 7)) << 3));
                f16x8 b1 = *(const f16x8*)(cb + (16 + l15) * 512 + ((ch ^ (l15 & 7)) << 3));
                f16x8 q = __builtin_bit_cast(f16x8, R[s]);
                S0 = MFMA16(q, b0, S0);
                S1 = MFMA16(q, b1, S1);
            }
            __builtin_amdgcn_s_setprio(0);
            // ---- wave-local softmax (rows w4*16 + g*4 + q) ----
            f32x4 tm, scl;
            #pragma unroll
            for (int q = 0; q < 4; ++q) tm[q] = fmaxf(S0[q], S1[q]);
            tm = rmax16(tm);
            #pragma unroll
            for (int q = 0; q < 4; ++q) {
                float mnew = fmaxf(m_run[q], tm[q]);
                scl[q] = __expf(m_run[q] - mnew);
                m_run[q] = mnew;
                S0[q] = __expf(S0[q] - mnew);
                S1[q] = __expf(S1[q] - mnew);
            }
            f32x4 ps;
            #pragma unroll
            for (int q = 0; q < 4; ++q) ps[q] = S0[q] + S1[q];
            ps = rsum16(ps);
            #pragma unroll
            for (int q = 0; q < 4; ++q) l_run[q] = l_run[q] * scl[q] + ps[q];
            if (l15 == 0) *(f32x4*)(SCL + cur * 64 + w4 * 16 + g * 4) = scl;
            // P write, chunk-swizzled
            f16* pp = PSB + cur * 2048;
            #pragma unroll
            for (int q = 0; q < 4; ++q) {
                int row = w4 * 16 + g * 4 + q;
                pp[row * 32 + ((((l15 >> 3) ^ g) << 3) | (l15 & 7))] = (f16)S0[q];
                pp[row * 32 + ((((2 + (l15 >> 3)) ^ g) << 3) | (l15 & 7))] = (f16)S1[q];
            }
        } else {
            // stage Dt(i) FIRST into DtB[cur]; PV below reads DtB[cur^1] (disjoint).
            // The iter-ending __syncthreads drains these loads WITH PV as cover.
            stage_Dt32(Dmb, DtB + cur * 16384, i * 32, w4, lane);
            if (i > 0) {
                // ---- PV(i-1): 64n x 128c per wave ----
                const int prev = cur ^ 1;
                const f16* pp = PSB + prev * 2048;
                const float* sc = SCL + prev * 64;
                f32x4 scl4[4];
                #pragma unroll
                for (int na = 0; na < 4; ++na)
                    scl4[na] = *(const f32x4*)(sc + na * 16 + g * 4);
                #pragma unroll
                for (int na = 0; na < 4; ++na)
                    #pragma unroll
                    for (int cb = 0; cb < 8; ++cb)
                        #pragma unroll
                        for (int q = 0; q < 4; ++q)
                            R[na * 8 + cb][q] *= scl4[na][q];
                f16x8 pa[4];
                #pragma unroll
                for (int na = 0; na < 4; ++na) {
                    int row = na * 16 + l15;
                    pa[na] = *(const f16x8*)(pp + row * 32 + ((g ^ (l15 >> 2)) << 3));
                }
                f16x8 d[8];
                #pragma unroll
                for (int cb = 0; cb < 8; ++cb)
                    d[cb] = *(const f16x8*)(DtB + prev * 16384 +
                                            (w4 * 128 + cb * 16 + l15) * 32 + (g << 3));
                __builtin_amdgcn_s_setprio(1);
                #pragma unroll
                for (int na = 0; na < 4; ++na)
                    #pragma unroll
                    for (int cb = 0; cb < 8; ++cb)
                        R[na * 8 + cb] = MFMA16(pa[na], d[cb], R[na * 8 + cb]);
                __builtin_amdgcn_s_setprio(0);
            }
        }
        __syncthreads();
    }

    // ---- epilogue E1: consumer does PV(127); producer publishes l ----
    if (isP) {
        if (l15 == 0) *(f32x4*)(LROW + w4 * 16 + g * 4) = l_run;
    } else {
        const f16* pp = PSB + 2048;            // prev = 127&1 = 1
        const float* sc = SCL + 64;
        f32x4 scl4[4];
        #pragma unroll
        for (int na = 0; na < 4; ++na)
            scl4[na] = *(const f32x4*)(sc + na * 16 + g * 4);
        #pragma unroll
        for (int na = 0; na < 4; ++na)
            #pragma unroll
            for (int cb = 0; cb < 8; ++cb)
                #pragma unroll
                for (int q = 0; q < 4; ++q)
                    R[na * 8 + cb][q] *= scl4[na][q];
        f16x8 pa[4];
        #pragma unroll
        for (int na = 0; na < 4; ++na) {
            int row = na * 16 + l15;
            pa[na] = *(const f16x8*)(pp + row * 32 + ((g ^ (l15 >> 2)) << 3));
        }
        f16x8 d[8];
        #pragma unroll
        for (int cb = 0; cb < 8; ++cb)
            d[cb] = *(const f16x8*)(DtB + 16384 +
                                    (w4 * 128 + cb * 16 + l15) * 32 + (g << 3));
        #pragma unroll
        for (int na = 0; na < 4; ++na)
            #pragma unroll
            for (int cb = 0; cb < 8; ++cb)
                R[na * 8 + cb] = MFMA16(pa[na], d[cb], R[na * 8 + cb]);
    }
    __syncthreads();

    // ---- E2: consumer writes T[c][n] = gamma * O / l ----
    const float gam = gamma_p[0];
    float* T = (float*)sm;                     // [512][68] f32 (LROW lives beyond)
    if (!isP) {
        #pragma unroll
        for (int na = 0; na < 4; ++na) {
            f32x4 lr = *(const f32x4*)(LROW + na * 16 + g * 4);
            f32x4 inv;
            #pragma unroll
            for (int q = 0; q < 4; ++q) inv[q] = gam / lr[q];
            #pragma unroll
            for (int cb = 0; cb < 8; ++cb) {
                int c = w4 * 128 + cb * 16 + l15;
                f32x4 v;
                #pragma unroll
                for (int q = 0; q < 4; ++q) v[q] = R[na * 8 + cb][q] * inv[q];
                *(f32x4*)(T + c * 68 + na * 16 + g * 4) = v;
            }
        }
    }
    __syncthreads();

    // ---- E3: all threads: out[c][n] = T + x ----
    const float* __restrict__ xb = x + (size_t)b * CC * NN;
    float* __restrict__ ob = out + (size_t)b * CC * NN;
    #pragma unroll
    for (int it = 0; it < 16; ++it) {
        int c = (t >> 4) + it * 32;
        int n4 = (t & 15) * 4;
        f32x4 v = *(const f32x4*)(T + c * 68 + n4);
        f32x4 xv = *(const f32x4*)(xb + (size_t)c * NN + n0 + n4);
        #pragma unroll
        for (int q = 0; q < 4; ++q) v[q] += xv[q];
        *(f32x4*)(ob + (size_t)c * NN + n0 + n4) = v;
    }
}

extern "C" void kernel_launch(void* const* d_in, const int* in_sizes, int n_in,
                              void* d_out, int out_size, void* d_ws, size_t ws_size,
                              hipStream_t stream) {
    const float* x  = (const float*)d_in[0];
    const float* Wb = (const float*)d_in[1];
    const float* Wc = (const float*)d_in[2];
    const float* Wd = (const float*)d_in[3];
    const float* gm = (const float*)d_in[4];
    float* out = (float*)d_out;
    char* ws = (char*)d_ws;

    // ws: W16 1.5MB | Bt 16MB | Ct 16MB | Dm 16MB  (~49.5MB)
    f16* W16 = (f16*)(ws);
    f16* Bt  = (f16*)(ws + 1572864);
    f16* Ct  = (f16*)(ws + 1572864 + 16777216);
    f16* Dm  = (f16*)(ws + 1572864 + 2 * 16777216);

    wcvt_k<<<dim3(768), 256, 0, stream>>>(Wb, Wc, Wd, W16);
    proj_k<<<dim3(32, 4, 12), 256, 0, stream>>>(x, W16, Bt, Ct, Dm);
    flash_k<<<dim3(256), 512, 0, stream>>>(x, gm, Bt, Ct, Dm, out);
}